// Round 1
// baseline (5994.323 us; speedup 1.0000x reference)
//
#include <hip/hip_runtime.h>

#define N_NODES 100000
#define N_EDGES 1600000
#define F_IN    32
#define HD      64
#define EPS     1e-5f

// ---------------- edge-index dtype probe ----------------
// If edge_index arrived as int64 (little-endian, values < 2^31), every odd
// int32 word of the first 64 entries is 0. If int32, those words are random
// node ids (all-zero probability ~0). Deterministic given fixed inputs.
__global__ void k_detect(const int* __restrict__ ei, int* __restrict__ flag) {
    if (threadIdx.x == 0 && blockIdx.x == 0) {
        int all_zero = 1;
        for (int k = 0; k < 64; ++k)
            if (ei[2 * k + 1] != 0) { all_zero = 0; break; }
        *flag = all_zero;   // 1 -> int64 layout, 0 -> int32 layout
    }
}

__device__ __forceinline__ int load_src(const int* ei, int e, int is64) {
    return is64 ? ei[2 * e] : ei[e];
}
__device__ __forceinline__ int load_dst(const int* ei, int e, int is64) {
    return is64 ? ei[2 * (N_EDGES + e)] : ei[N_EDGES + e];
}

// ---------------- degree + norm ----------------
__global__ void k_deg(const int* __restrict__ ei, const int* __restrict__ flag,
                      float* __restrict__ deg) {
    int e = blockIdx.x * blockDim.x + threadIdx.x;
    if (e >= N_EDGES) return;
    int is64 = *flag;
    int d = load_dst(ei, e, is64);
    atomicAdd(&deg[d], 1.0f);
}

__global__ void k_dinv(const float* __restrict__ deg, float* __restrict__ dinv) {
    int n = blockIdx.x * blockDim.x + threadIdx.x;
    if (n >= N_NODES) return;
    dinv[n] = rsqrtf(deg[n] + 1.0f);
}

// ---------------- node embedding: h = x @ W_embed + b ----------------
// block = 256 = 4 nodes x 64 cols
__global__ void k_embed(const float* __restrict__ x, const float* __restrict__ W,
                        const float* __restrict__ b, float* __restrict__ h) {
    __shared__ float Ws[F_IN * HD];   // 8 KB
    __shared__ float xs[4 * F_IN];    // 512 B
    int t = threadIdx.x;
    for (int i = t; i < F_IN * HD; i += 256) Ws[i] = W[i];
    if (t < 4 * F_IN) {
        int r = t >> 5, c = t & 31;
        int node = blockIdx.x * 4 + r;
        xs[t] = (node < N_NODES) ? x[node * F_IN + c] : 0.f;
    }
    __syncthreads();
    int r = t >> 6, j = t & 63;
    int node = blockIdx.x * 4 + r;
    float acc = b[j];
#pragma unroll
    for (int k = 0; k < F_IN; ++k)
        acc = fmaf(xs[r * F_IN + k], Ws[k * HD + j], acc);
    if (node < N_NODES) h[node * HD + j] = acc;
}

// ---------------- 64x64 GEMM: C = A @ W ----------------
// block = 256 = 4 rows x 64 cols; W staged in LDS (16 KB), A rows in LDS
__global__ void k_gemm64(const float* __restrict__ A, const float* __restrict__ W,
                         float* __restrict__ C) {
    __shared__ float Ws[HD * HD];   // 16 KB
    __shared__ float As[4 * HD];    // 1 KB
    int t = threadIdx.x;
    for (int i = t; i < HD * HD; i += 256) Ws[i] = W[i];
    {
        int r = t >> 6, c = t & 63;
        int node = blockIdx.x * 4 + r;
        As[t] = (node < N_NODES) ? A[node * HD + c] : 0.f;
    }
    __syncthreads();
    int r = t >> 6, j = t & 63;
    int node = blockIdx.x * 4 + r;
    float acc = 0.f;
#pragma unroll
    for (int k = 0; k < HD; ++k)
        acc = fmaf(As[r * HD + k], Ws[k * HD + j], acc);
    if (node < N_NODES) C[node * HD + j] = acc;
}

// ---------------- agg init: agg = xw * self_norm + conv_b ----------------
__global__ void k_agg_init(const float4* __restrict__ xw, const float* __restrict__ dinv,
                           const float* __restrict__ cb, float4* __restrict__ agg) {
    int i = blockIdx.x * blockDim.x + threadIdx.x;   // over N*16 float4s
    if (i >= N_NODES * 16) return;
    int n = i >> 4, q = i & 15;
    float d = dinv[n];
    float sn = d * d;
    float4 v = xw[i];
    const float* cbp = cb + q * 4;
    float4 r;
    r.x = fmaf(v.x, sn, cbp[0]);
    r.y = fmaf(v.y, sn, cbp[1]);
    r.z = fmaf(v.z, sn, cbp[2]);
    r.w = fmaf(v.w, sn, cbp[3]);
    agg[i] = r;
}

// ---------------- edge scatter: agg[dst] += xw[src] * norm_e ----------------
// one thread per (edge, float4-chunk): 16 threads/edge
__global__ void k_scatter(const float* __restrict__ xw, const int* __restrict__ ei,
                          const int* __restrict__ flag, const float* __restrict__ dinv,
                          float* __restrict__ agg) {
    int i = blockIdx.x * blockDim.x + threadIdx.x;   // over E*16
    if (i >= N_EDGES * 16) return;
    int e = i >> 4, q = i & 15;
    int is64 = *flag;
    int s = load_src(ei, e, is64);
    int d = load_dst(ei, e, is64);
    float ne = dinv[s] * dinv[d];
    float4 v = *(const float4*)(xw + s * HD + q * 4);
    float* p = agg + d * HD + q * 4;
    atomicAdd(p + 0, v.x * ne);
    atomicAdd(p + 1, v.y * ne);
    atomicAdd(p + 2, v.z * ne);
    atomicAdd(p + 3, v.w * ne);
}

// ---------------- BN stats: per-column sum & sumsq ----------------
__global__ void k_bn_stats(const float* __restrict__ h, float* __restrict__ stats) {
    int t = threadIdx.x;
    int j = t & 63, rg = t >> 6;
    float s = 0.f, s2 = 0.f;
    for (int n = blockIdx.x * 4 + rg; n < N_NODES; n += gridDim.x * 4) {
        float v = h[n * HD + j];
        s += v;
        s2 = fmaf(v, v, s2);
    }
    __shared__ float ls[256], ls2[256];
    ls[t] = s; ls2[t] = s2;
    __syncthreads();
    if (t < 64) {
        s  = ls[t] + ls[t + 64] + ls[t + 128] + ls[t + 192];
        s2 = ls2[t] + ls2[t + 64] + ls2[t + 128] + ls2[t + 192];
        atomicAdd(&stats[j], s);
        atomicAdd(&stats[64 + j], s2);
    }
}

// ---------------- BN apply + ReLU (in place) ----------------
__global__ void k_bn_apply(float4* __restrict__ h, const float* __restrict__ stats,
                           const float* __restrict__ gamma, const float* __restrict__ beta) {
    int i = blockIdx.x * blockDim.x + threadIdx.x;   // over N*16
    if (i >= N_NODES * 16) return;
    int q = i & 15;
    float4 v = h[i];
    float* vv = (float*)&v;
#pragma unroll
    for (int u = 0; u < 4; ++u) {
        int j = q * 4 + u;
        float mu  = stats[j] * (1.0f / N_NODES);
        float var = stats[64 + j] * (1.0f / N_NODES) - mu * mu;
        float tv  = gamma[j] * (vv[u] - mu) * rsqrtf(var + EPS) + beta[j];
        vv[u] = fmaxf(tv, 0.f);
    }
    h[i] = v;
}

// ---------------- mean pool (sum; divide in k_out) ----------------
__global__ void k_pool(const float* __restrict__ h, float* __restrict__ pooled) {
    int t = threadIdx.x;
    int j = t & 63, rg = t >> 6;
    float s = 0.f;
    for (int n = blockIdx.x * 4 + rg; n < N_NODES; n += gridDim.x * 4)
        s += h[n * HD + j];
    __shared__ float ls[256];
    ls[t] = s;
    __syncthreads();
    if (t < 64)
        atomicAdd(&pooled[j], ls[t] + ls[t + 64] + ls[t + 128] + ls[t + 192]);
}

// ---------------- output: (pooled/N) @ W_out + b_out ----------------
__global__ void k_out(const float* __restrict__ pooled, const float* __restrict__ Wout,
                      const float* __restrict__ bout, float* __restrict__ out) {
    int o = threadIdx.x;   // 64 threads
    float acc = bout[o];
#pragma unroll
    for (int k = 0; k < HD; ++k)
        acc = fmaf(pooled[k] * (1.0f / N_NODES), Wout[k * HD + o], acc);
    out[o] = acc;
}

extern "C" void kernel_launch(void* const* d_in, const int* in_sizes, int n_in,
                              void* d_out, int out_size, void* d_ws, size_t ws_size,
                              hipStream_t stream) {
    const float* x        = (const float*)d_in[0];
    const int*   ei       = (const int*)  d_in[1];
    const float* W_embed  = (const float*)d_in[2];
    const float* b_embed  = (const float*)d_in[3];
    const float* conv_W   = (const float*)d_in[4];
    const float* conv_b   = (const float*)d_in[5];
    const float* bn_gamma = (const float*)d_in[6];
    const float* bn_beta  = (const float*)d_in[7];
    const float* W_out    = (const float*)d_in[8];
    const float* b_out    = (const float*)d_in[9];
    float* out = (float*)d_out;

    float* ws    = (float*)d_ws;
    float* deg   = ws;                       // N
    float* dinv  = ws + N_NODES;             // N
    float* stats = ws + 2 * N_NODES;         // sum[64], sumsq[64], pooled[64]
    int*   flag  = (int*)(ws + 2 * N_NODES + 192);
    float* bufA  = ws + 2 * N_NODES + 256;   // N*64  (h / agg)
    float* bufB  = bufA + N_NODES * HD;      // N*64  (xw)

    hipMemsetAsync(deg, 0, N_NODES * sizeof(float), stream);
    k_detect<<<1, 64, 0, stream>>>(ei, flag);
    k_deg<<<(N_EDGES + 255) / 256, 256, 0, stream>>>(ei, flag, deg);
    k_dinv<<<(N_NODES + 255) / 256, 256, 0, stream>>>(deg, dinv);
    k_embed<<<(N_NODES + 3) / 4, 256, 0, stream>>>(x, W_embed, b_embed, bufA);

    for (int l = 0; l < 4; ++l) {
        k_gemm64<<<(N_NODES + 3) / 4, 256, 0, stream>>>(bufA, conv_W + l * HD * HD, bufB);
        k_agg_init<<<(N_NODES * 16 + 255) / 256, 256, 0, stream>>>(
            (const float4*)bufB, dinv, conv_b + l * HD, (float4*)bufA);
        k_scatter<<<(N_EDGES * 16 + 255) / 256, 256, 0, stream>>>(bufB, ei, flag, dinv, bufA);
        hipMemsetAsync(stats, 0, 128 * sizeof(float), stream);
        k_bn_stats<<<1024, 256, 0, stream>>>(bufA, stats);
        k_bn_apply<<<(N_NODES * 16 + 255) / 256, 256, 0, stream>>>(
            (float4*)bufA, stats, bn_gamma + l * HD, bn_beta + l * HD);
    }

    hipMemsetAsync(stats + 128, 0, 64 * sizeof(float), stream);
    k_pool<<<1024, 256, 0, stream>>>(bufA, stats + 128);
    k_out<<<1, 64, 0, stream>>>(stats + 128, W_out, b_out, out);
}

// Round 2
// 1247.252 us; speedup vs baseline: 4.8060x; 4.8060x over previous
//
#include <hip/hip_runtime.h>

#define N_NODES 100000
#define N_EDGES 1600000
#define F_IN    32
#define HD      64
#define EPS     1e-5f

// ---------------- edge-index dtype probe ----------------
// If edge_index arrived as int64 (LE, values < 2^31), every odd int32 word of
// the first 64 entries is 0. If int32, those are random node ids (~never 0).
__global__ void k_detect(const int* __restrict__ ei, int* __restrict__ flag) {
    if (threadIdx.x == 0 && blockIdx.x == 0) {
        int all_zero = 1;
        for (int k = 0; k < 64; ++k)
            if (ei[2 * k + 1] != 0) { all_zero = 0; break; }
        *flag = all_zero;   // 1 -> int64 layout, 0 -> int32 layout
    }
}

__device__ __forceinline__ int load_src(const int* ei, int e, int is64) {
    return is64 ? ei[2 * e] : ei[e];
}
__device__ __forceinline__ int load_dst(const int* ei, int e, int is64) {
    return is64 ? ei[2 * (N_EDGES + e)] : ei[N_EDGES + e];
}

// ---------------- degree histogram (int) ----------------
__global__ void k_deg(const int* __restrict__ ei, const int* __restrict__ flag,
                      int* __restrict__ deg) {
    int e = blockIdx.x * blockDim.x + threadIdx.x;
    if (e >= N_EDGES) return;
    int is64 = *flag;
    atomicAdd(&deg[load_dst(ei, e, is64)], 1);
}

__global__ void k_dinv(const int* __restrict__ deg, float* __restrict__ dinv) {
    int n = blockIdx.x * blockDim.x + threadIdx.x;
    if (n >= N_NODES) return;
    dinv[n] = rsqrtf((float)deg[n] + 1.0f);
}

// ---------------- single-block exclusive scan deg -> row_start ----------------
__global__ void k_scan(const int* __restrict__ deg, int* __restrict__ row_start) {
    __shared__ int bs[1024];
    int t = threadIdx.x;
    const int CH = (N_NODES + 1023) / 1024;
    int beg = t * CH, end = min(beg + CH, N_NODES);
    int s = 0;
    for (int i = beg; i < end; ++i) s += deg[i];
    bs[t] = s;
    __syncthreads();
    for (int off = 1; off < 1024; off <<= 1) {
        int v = (t >= off) ? bs[t - off] : 0;
        __syncthreads();
        bs[t] += v;
        __syncthreads();
    }
    int base = (t == 0) ? 0 : bs[t - 1];
    for (int i = beg; i < end; ++i) { row_start[i] = base; base += deg[i]; }
    if (t == 0) row_start[N_NODES] = bs[1023];
}

__global__ void k_copy_cursor(const int* __restrict__ row_start, int* __restrict__ cursor) {
    int n = blockIdx.x * blockDim.x + threadIdx.x;
    if (n < N_NODES) cursor[n] = row_start[n];
}

// ---------------- bucket edges into CSR ----------------
__global__ void k_bucket(const int* __restrict__ ei, const int* __restrict__ flag,
                         int* __restrict__ cursor, int* __restrict__ csr_src) {
    int e = blockIdx.x * blockDim.x + threadIdx.x;
    if (e >= N_EDGES) return;
    int is64 = *flag;
    int s = load_src(ei, e, is64);
    int d = load_dst(ei, e, is64);
    int pos = atomicAdd(&cursor[d], 1);
    csr_src[pos] = s;
}

// ---------------- node embedding: h = x @ W_embed + b ----------------
__global__ void k_embed(const float* __restrict__ x, const float* __restrict__ W,
                        const float* __restrict__ b, float* __restrict__ h) {
    __shared__ float Ws[F_IN * HD];
    __shared__ float xs[4 * F_IN];
    int t = threadIdx.x;
    for (int i = t; i < F_IN * HD; i += 256) Ws[i] = W[i];
    if (t < 4 * F_IN) {
        int r = t >> 5, c = t & 31;
        int node = blockIdx.x * 4 + r;
        xs[t] = (node < N_NODES) ? x[node * F_IN + c] : 0.f;
    }
    __syncthreads();
    int r = t >> 6, j = t & 63;
    int node = blockIdx.x * 4 + r;
    float acc = b[j];
#pragma unroll
    for (int k = 0; k < F_IN; ++k)
        acc = fmaf(xs[r * F_IN + k], Ws[k * HD + j], acc);
    if (node < N_NODES) h[node * HD + j] = acc;
}

// ---------------- 64x64 GEMM: C = A @ W ----------------
__global__ void k_gemm64(const float* __restrict__ A, const float* __restrict__ W,
                         float* __restrict__ C) {
    __shared__ float Ws[HD * HD];
    __shared__ float As[4 * HD];
    int t = threadIdx.x;
    for (int i = t; i < HD * HD; i += 256) Ws[i] = W[i];
    {
        int r = t >> 6, c = t & 63;
        int node = blockIdx.x * 4 + r;
        As[t] = (node < N_NODES) ? A[node * HD + c] : 0.f;
    }
    __syncthreads();
    int r = t >> 6, j = t & 63;
    int node = blockIdx.x * 4 + r;
    float acc = 0.f;
#pragma unroll
    for (int k = 0; k < HD; ++k)
        acc = fmaf(As[r * HD + k], Ws[k * HD + j], acc);
    if (node < N_NODES) C[node * HD + j] = acc;
}

// ---------------- CSR gather-aggregate ----------------
// one wave per dst node; lane j owns column j
// h[n] = conv_b + dinv[n]^2 * xw[n] + dinv[n] * sum_e dinv[src_e] * xw[src_e]
__global__ void __launch_bounds__(256)
k_gather(const float* __restrict__ xw, const int* __restrict__ row_start,
         const int* __restrict__ csr_src, const float* __restrict__ dinv,
         const float* __restrict__ cb, float* __restrict__ h) {
    int wid = threadIdx.x >> 6;
    int lane = threadIdx.x & 63;
    int n = blockIdx.x * 4 + wid;
    if (n >= N_NODES) return;
    int beg = row_start[n], end = row_start[n + 1];
    float dn = dinv[n];
    float acc = xw[n * HD + lane] * (dn * dn);
    for (int base = beg; base < end; base += 64) {
        int cnt = min(64, end - base);
        int s = 0; float dv = 0.f;
        if (lane < cnt) { s = csr_src[base + lane]; dv = dinv[s]; }
        for (int k = 0; k < cnt; ++k) {
            int sk = __shfl(s, k);
            float nek = __shfl(dv, k) * dn;
            acc = fmaf(nek, xw[sk * HD + lane], acc);
        }
    }
    h[n * HD + lane] = acc + cb[lane];
}

// ---------------- BN stats: per-column sum & sumsq ----------------
__global__ void k_bn_stats(const float* __restrict__ h, float* __restrict__ stats) {
    int t = threadIdx.x;
    int j = t & 63, rg = t >> 6;
    float s = 0.f, s2 = 0.f;
    for (int n = blockIdx.x * 4 + rg; n < N_NODES; n += gridDim.x * 4) {
        float v = h[n * HD + j];
        s += v;
        s2 = fmaf(v, v, s2);
    }
    __shared__ float ls[256], ls2[256];
    ls[t] = s; ls2[t] = s2;
    __syncthreads();
    if (t < 64) {
        s  = ls[t] + ls[t + 64] + ls[t + 128] + ls[t + 192];
        s2 = ls2[t] + ls2[t + 64] + ls2[t + 128] + ls2[t + 192];
        atomicAdd(&stats[j], s);
        atomicAdd(&stats[64 + j], s2);
    }
}

// ---------------- BN apply + ReLU (in place) ----------------
__global__ void k_bn_apply(float4* __restrict__ h, const float* __restrict__ stats,
                           const float* __restrict__ gamma, const float* __restrict__ beta) {
    int i = blockIdx.x * blockDim.x + threadIdx.x;
    if (i >= N_NODES * 16) return;
    int q = i & 15;
    float4 v = h[i];
    float* vv = (float*)&v;
#pragma unroll
    for (int u = 0; u < 4; ++u) {
        int j = q * 4 + u;
        float mu  = stats[j] * (1.0f / N_NODES);
        float var = stats[64 + j] * (1.0f / N_NODES) - mu * mu;
        float tv  = gamma[j] * (vv[u] - mu) * rsqrtf(var + EPS) + beta[j];
        vv[u] = fmaxf(tv, 0.f);
    }
    h[i] = v;
}

// ---------------- mean pool ----------------
__global__ void k_pool(const float* __restrict__ h, float* __restrict__ pooled) {
    int t = threadIdx.x;
    int j = t & 63, rg = t >> 6;
    float s = 0.f;
    for (int n = blockIdx.x * 4 + rg; n < N_NODES; n += gridDim.x * 4)
        s += h[n * HD + j];
    __shared__ float ls[256];
    ls[t] = s;
    __syncthreads();
    if (t < 64)
        atomicAdd(&pooled[j], ls[t] + ls[t + 64] + ls[t + 128] + ls[t + 192]);
}

// ---------------- output ----------------
__global__ void k_out(const float* __restrict__ pooled, const float* __restrict__ Wout,
                      const float* __restrict__ bout, float* __restrict__ out) {
    int o = threadIdx.x;
    float acc = bout[o];
#pragma unroll
    for (int k = 0; k < HD; ++k)
        acc = fmaf(pooled[k] * (1.0f / N_NODES), Wout[k * HD + o], acc);
    out[o] = acc;
}

extern "C" void kernel_launch(void* const* d_in, const int* in_sizes, int n_in,
                              void* d_out, int out_size, void* d_ws, size_t ws_size,
                              hipStream_t stream) {
    const float* x        = (const float*)d_in[0];
    const int*   ei       = (const int*)  d_in[1];
    const float* W_embed  = (const float*)d_in[2];
    const float* b_embed  = (const float*)d_in[3];
    const float* conv_W   = (const float*)d_in[4];
    const float* conv_b   = (const float*)d_in[5];
    const float* bn_gamma = (const float*)d_in[6];
    const float* bn_beta  = (const float*)d_in[7];
    const float* W_out    = (const float*)d_in[8];
    const float* b_out    = (const float*)d_in[9];
    float* out = (float*)d_out;

    float* ws = (float*)d_ws;
    // layout (element offsets, all 4B):
    int*   degcur    = (int*)ws;                         // N   (deg, then cursor)
    float* dinv      = ws + N_NODES;                     // N
    int*   row_start = (int*)(ws + 2 * N_NODES);         // N+1 (pad to N+4)
    float* stats     = ws + 3 * N_NODES + 8;             // 192 floats
    int*   flag      = (int*)(ws + 3 * N_NODES + 200);
    int*   csr_src   = (int*)(ws + 3 * N_NODES + 256);   // E
    float* bufA      = ws + 3 * N_NODES + 256 + N_EDGES; // N*64
    float* bufB      = bufA + N_NODES * HD;              // N*64

    hipMemsetAsync(degcur, 0, N_NODES * sizeof(int), stream);
    k_detect<<<1, 64, 0, stream>>>(ei, flag);
    k_deg<<<(N_EDGES + 255) / 256, 256, 0, stream>>>(ei, flag, degcur);
    k_dinv<<<(N_NODES + 255) / 256, 256, 0, stream>>>(degcur, dinv);
    k_scan<<<1, 1024, 0, stream>>>(degcur, row_start);
    k_embed<<<(N_NODES + 3) / 4, 256, 0, stream>>>(x, W_embed, b_embed, bufA);
    k_copy_cursor<<<(N_NODES + 255) / 256, 256, 0, stream>>>(row_start, degcur);
    k_bucket<<<(N_EDGES + 255) / 256, 256, 0, stream>>>(ei, flag, degcur, csr_src);

    for (int l = 0; l < 4; ++l) {
        k_gemm64<<<(N_NODES + 3) / 4, 256, 0, stream>>>(bufA, conv_W + l * HD * HD, bufB);
        k_gather<<<(N_NODES + 3) / 4, 256, 0, stream>>>(bufB, row_start, csr_src, dinv,
                                                        conv_b + l * HD, bufA);
        hipMemsetAsync(stats, 0, 128 * sizeof(float), stream);
        k_bn_stats<<<1024, 256, 0, stream>>>(bufA, stats);
        k_bn_apply<<<(N_NODES * 16 + 255) / 256, 256, 0, stream>>>(
            (float4*)bufA, stats, bn_gamma + l * HD, bn_beta + l * HD);
    }

    hipMemsetAsync(stats + 128, 0, 64 * sizeof(float), stream);
    k_pool<<<1024, 256, 0, stream>>>(bufA, stats + 128);
    k_out<<<1, 64, 0, stream>>>(stats + 128, W_out, b_out, out);
}